// Round 2
// baseline (479.834 us; speedup 1.0000x reference)
//
#include <hip/hip_runtime.h>
#include <hip/hip_bf16.h>

#define N_NODES 100000
#define N_EDGES 1600000
#define IN_DIM  128
#define HID     64
#define BIN_NODES 256
#define NBINS   ((N_NODES + BIN_NODES - 1) / BIN_NODES)   // 391
#define EB      2048       // edges per block in bin_hist / bin_scatter

#define PITCH_IN  152      // bf16 units per LDS row for K=128 (+24 pad: 2-way banks, 16B-aligned)
#define PITCH_HID 88       // bf16 units per LDS row for K=64  (+24 pad)

typedef __attribute__((ext_vector_type(8))) short bf16x8;   // MFMA A/B frag (4 VGPRs)
typedef __attribute__((ext_vector_type(4))) float f32x4;    // MFMA C/D frag

__device__ inline unsigned short f2bf(float f) {
    __hip_bfloat16 b = __float2bfloat16(f);
    return *reinterpret_cast<unsigned short*>(&b);
}

// ---------------------------------------------------------------------------
// Pre-pack W matrices into B-fragment order bf16:
// flat = (((kc*4 + nt)*4 + quad)*16 + n16)*8 + j ;  k = kc*32+quad*8+j, n = nt*16+n16
// ---------------------------------------------------------------------------
__global__ void wf_prep_kernel(const float* __restrict__ Wi,
                               const float* __restrict__ W1,
                               const float* __restrict__ W2,
                               const float* __restrict__ W3,
                               unsigned short* __restrict__ wf_in,
                               unsigned short* __restrict__ wf_hid) {
    int t = blockIdx.x * 256 + threadIdx.x;
    if (t < 8192) {  // Wi: K=128 -> kc in 0..3
        int j = t & 7, n16 = (t >> 3) & 15, quad = (t >> 7) & 3, nt = (t >> 9) & 3, kc = t >> 11;
        int k = kc * 32 + quad * 8 + j, n = nt * 16 + n16;
        wf_in[t] = f2bf(Wi[k * HID + n]);
    }
    if (t < 4096) {  // W1..W3: K=64 -> kc in 0..1
        int j = t & 7, n16 = (t >> 3) & 15, quad = (t >> 7) & 3, nt = (t >> 9) & 3, kc = t >> 11;
        int k = kc * 32 + quad * 8 + j, n = nt * 16 + n16;
        wf_hid[t]        = f2bf(W1[k * HID + n]);
        wf_hid[4096 + t] = f2bf(W2[k * HID + n]);
        wf_hid[8192 + t] = f2bf(W3[k * HID + n]);
    }
}

// ---------------------------------------------------------------------------
// h0 = relu(x @ Wi + bi) via bf16 MFMA. Block = 64 rows, wave = 16 rows.
// ---------------------------------------------------------------------------
__global__ __launch_bounds__(256) void gemm_in_kernel(
        const float* __restrict__ x,
        const unsigned short* __restrict__ wf,   // fragment-order Wi (bf16 bits)
        const float* __restrict__ bi,
        float* __restrict__ h0,
        __hip_bfloat16* __restrict__ hbf) {
    __shared__ unsigned short sX[64 * PITCH_IN];   // 19456 B
    const int tid  = threadIdx.x;
    const int row0 = blockIdx.x * 64;

    // Stage x tile (64 x 128 f32 -> bf16), coalesced float4 reads, 8B LDS writes.
    #pragma unroll
    for (int it = 0; it < 8; ++it) {
        int i  = tid + it * 256;
        int r  = i >> 5;        // 32 float4 per row
        int kq = i & 31;
        int rg = row0 + r;
        float4 v = (rg < N_NODES)
                 ? ((const float4*)x)[(size_t)rg * (IN_DIM / 4) + kq]
                 : make_float4(0.f, 0.f, 0.f, 0.f);
        ushort4 pk;
        pk.x = f2bf(v.x); pk.y = f2bf(v.y); pk.z = f2bf(v.z); pk.w = f2bf(v.w);
        *(ushort4*)(sX + r * PITCH_IN + kq * 4) = pk;
    }
    __syncthreads();

    const int lane = tid & 63;
    const int wid  = tid >> 6;
    const int l16  = lane & 15;
    const int q    = lane >> 4;

    f32x4 acc[4] = {{0,0,0,0},{0,0,0,0},{0,0,0,0},{0,0,0,0}};
    const bf16x8* wf8 = (const bf16x8*)wf;

    #pragma unroll
    for (int kc = 0; kc < 4; ++kc) {
        bf16x8 af = *(const bf16x8*)(sX + (wid * 16 + l16) * PITCH_IN + kc * 32 + q * 8);
        #pragma unroll
        for (int nt = 0; nt < 4; ++nt) {
            bf16x8 bfr = wf8[((kc * 4 + nt) * 4 + q) * 16 + l16];
            acc[nt] = __builtin_amdgcn_mfma_f32_16x16x32_bf16(af, bfr, acc[nt], 0, 0, 0);
        }
    }

    // Epilogue: C/D layout col = lane&15, row = quad*4 + reg  [m89]
    #pragma unroll
    for (int nt = 0; nt < 4; ++nt) {
        float bb = bi[nt * 16 + l16];
        #pragma unroll
        for (int reg = 0; reg < 4; ++reg) {
            int rg = row0 + wid * 16 + q * 4 + reg;
            if (rg < N_NODES) {
                float v = fmaxf(acc[nt][reg] + bb, 0.0f);
                h0 [(size_t)rg * HID + nt * 16 + l16] = v;
                hbf[(size_t)rg * HID + nt * 16 + l16] = __float2bfloat16(v);
            }
        }
    }
}

// ---------------------------------------------------------------------------
// Binned CSR build.  Record: high32 = w bits, low32 = (local_tgt<<17) | src.
// ---------------------------------------------------------------------------
__global__ void bin_hist_kernel(const int* __restrict__ tgt,
                                int* __restrict__ g_bin_cnt) {
    __shared__ int cnt[NBINS];
    for (int i = threadIdx.x; i < NBINS; i += 256) cnt[i] = 0;
    __syncthreads();
    const int e0 = blockIdx.x * EB;
    for (int i = threadIdx.x; i < EB; i += 256) {
        int e = e0 + i;
        if (e < N_EDGES) atomicAdd(&cnt[tgt[e] >> 8], 1);
    }
    __syncthreads();
    for (int i = threadIdx.x; i < NBINS; i += 256)
        if (cnt[i]) atomicAdd(&g_bin_cnt[i], cnt[i]);
}

__global__ void bin_scan_kernel(const int* __restrict__ g_bin_cnt,
                                int* __restrict__ g_bin_offs,
                                int* __restrict__ g_bin_cursor) {
    __shared__ int s[512];
    const int tid = threadIdx.x;
    int v = (tid < NBINS) ? g_bin_cnt[tid] : 0;
    s[tid] = v;
    __syncthreads();
    for (int off = 1; off < 512; off <<= 1) {
        int t = (tid >= off) ? s[tid - off] : 0;
        __syncthreads();
        s[tid] += t;
        __syncthreads();
    }
    if (tid < NBINS) { g_bin_offs[tid] = s[tid] - v; g_bin_cursor[tid] = s[tid] - v; }
}

__global__ void bin_scatter_kernel(const int* __restrict__ src,
                                   const int* __restrict__ tgt,
                                   const float* __restrict__ ea,
                                   int* __restrict__ g_bin_cursor,
                                   unsigned long long* __restrict__ binned) {
    __shared__ int cnt[NBINS];
    __shared__ int base[NBINS];
    __shared__ int cur[NBINS];
    for (int i = threadIdx.x; i < NBINS; i += 256) cnt[i] = 0;
    __syncthreads();

    const int e0 = blockIdx.x * EB;
    int myb[EB / 256];
    unsigned long long myrec[EB / 256];
    #pragma unroll
    for (int i = 0; i < EB / 256; ++i) {
        int e = e0 + threadIdx.x + i * 256;
        if (e < N_EDGES) {
            int t = tgt[e];
            int b = t >> 8;
            myb[i] = b;
            myrec[i] = ((unsigned long long)(unsigned)__float_as_int(ea[e]) << 32)
                     | ((unsigned)(t & 255) << 17) | (unsigned)src[e];
            atomicAdd(&cnt[b], 1);
        } else {
            myb[i] = -1;
        }
    }
    __syncthreads();
    for (int i = threadIdx.x; i < NBINS; i += 256) {
        cur[i]  = 0;
        base[i] = cnt[i] ? atomicAdd(&g_bin_cursor[i], cnt[i]) : 0;
    }
    __syncthreads();
    #pragma unroll
    for (int i = 0; i < EB / 256; ++i) {
        if (myb[i] >= 0) {
            int r = atomicAdd(&cur[myb[i]], 1);
            binned[base[myb[i]] + r] = myrec[i];
        }
    }
}

// 1024 threads/block (vs 256): 391 blocks is only ~1.5 blocks/CU, so widen
// each block to 16 waves to restore occupancy for the two edge-sweep loops.
__global__ __launch_bounds__(1024) void fine_fill_kernel(
                                 const unsigned long long* __restrict__ binned,
                                 const int* __restrict__ g_bin_offs,
                                 const int* __restrict__ g_bin_cnt,
                                 int* __restrict__ offs,
                                 int* __restrict__ counts,
                                 unsigned long long* __restrict__ pairs) {
    __shared__ int ncnt[256];
    __shared__ int nbase[256];
    __shared__ int wsum[4];
    const int b    = blockIdx.x;
    const int tid  = threadIdx.x;
    const int ebeg = g_bin_offs[b];
    const int ecnt = g_bin_cnt[b];

    if (tid < 256) ncnt[tid] = 0;
    __syncthreads();
    for (int i = tid; i < ecnt; i += 1024) {
        int lt = (int)((binned[ebeg + i] >> 17) & 255);
        atomicAdd(&ncnt[lt], 1);
    }
    __syncthreads();

    if (tid < 256) {   // wave-uniform guard: waves 0-3 only
        const int lane = tid & 63, wid = tid >> 6;
        int v  = ncnt[tid];
        int sc = v;
        #pragma unroll
        for (int d = 1; d < 64; d <<= 1) {
            int t = __shfl_up(sc, d);
            if (lane >= d) sc += t;
        }
        if (lane == 63) wsum[wid] = sc;
        __syncthreads();
        int wb = 0;
        for (int w = 0; w < wid; ++w) wb += wsum[w];
        int excl = wb + sc - v;
        nbase[tid] = excl;

        const int node = b * BIN_NODES + tid;
        if (node < N_NODES) { offs[node] = ebeg + excl; counts[node] = v; }

        ncnt[tid] = 0;  // reuse as cursor
    } else {
        __syncthreads();
    }
    __syncthreads();
    for (int i = tid; i < ecnt; i += 1024) {
        unsigned long long rec = binned[ebeg + i];
        int lt = (int)((rec >> 17) & 255);
        int r  = atomicAdd(&ncnt[lt], 1);
        pairs[ebeg + nbase[lt] + r] =
            (rec & 0xFFFFFFFF00000000ull) | (rec & 0x1FFFFull);
    }
}

// ---------------------------------------------------------------------------
// FUSED: a = h + segment_sum(bf16(h)[src] * w) ; hnext = relu(a @ W + b).
// Phase 1 is latency-bound (random 128B row gathers, mostly L2-miss/L3-hit):
//  - 4 edges in flight per 16-lane group (16/wave/iter), same FP sum order
//  - offs/counts for the wave's 16 nodes preloaded once, shfl-broadcast
//  - h float4 load hoisted above the gather loop
// ---------------------------------------------------------------------------
__global__ __launch_bounds__(256) void agg_gemm_kernel(
        const float* __restrict__ h,               // layer-l activations (f32)
        const __hip_bfloat16* __restrict__ hbf_in, // layer-l activations (bf16)
        const int* __restrict__ offs,
        const int* __restrict__ counts,
        const int2* __restrict__ pairs,
        const unsigned short* __restrict__ wf,     // fragment-order W (bf16 bits)
        const float* __restrict__ b,
        float* __restrict__ hnext,
        __hip_bfloat16* __restrict__ hbf_out,
        const int store_bf) {
    __shared__ unsigned short sX[64 * PITCH_HID];  // 11264 B
    const int tid  = threadIdx.x;
    const int row0 = blockIdx.x * 64;
    const int lane = tid & 63;
    const int wid  = tid >> 6;
    const int grp  = lane >> 4;
    const int sub  = lane & 15;

    // Preload this wave's 16 node descriptors (lanes 0-15), broadcast via shfl.
    int offv = 0, cntv = 0;
    {
        int nl = row0 + wid * 16 + (lane & 15);
        if (lane < 16 && nl < N_NODES) { offv = offs[nl]; cntv = counts[nl]; }
    }

    // ---- Phase 1: aggregate 16 nodes per wave into LDS (bf16) ----
    for (int t = 0; t < 16; ++t) {
        const int node = row0 + wid * 16 + t;      // wave-uniform
        if (node < N_NODES) {
            const int beg = __shfl(offv, t);
            const int cnt = __shfl(cntv, t);
            float4 hv;
            if (grp == 0) hv = *(const float4*)(h + (size_t)node * HID + sub * 4);
            float ax = 0.f, ay = 0.f, az = 0.f, aw = 0.f;
            if (cnt > 0) {
                const int last = cnt - 1;
                for (int i = 0; i < cnt; i += 16) {
                    int e0 = i + grp;
                    int e1 = i + 4 + grp;
                    int e2 = i + 8 + grp;
                    int e3 = i + 12 + grp;
                    bool l0 = (e0 <= last);
                    bool l1 = (e1 <= last);
                    bool l2 = (e2 <= last);
                    bool l3 = (e3 <= last);
                    int2 p0 = pairs[beg + (l0 ? e0 : last)];
                    int2 p1 = pairs[beg + (l1 ? e1 : last)];
                    int2 p2 = pairs[beg + (l2 ? e2 : last)];
                    int2 p3 = pairs[beg + (l3 ? e3 : last)];
                    uint2 g0 = *(const uint2*)(hbf_in + (size_t)p0.x * HID + sub * 4);
                    uint2 g1 = *(const uint2*)(hbf_in + (size_t)p1.x * HID + sub * 4);
                    uint2 g2 = *(const uint2*)(hbf_in + (size_t)p2.x * HID + sub * 4);
                    uint2 g3 = *(const uint2*)(hbf_in + (size_t)p3.x * HID + sub * 4);
                    float w0 = l0 ? __int_as_float(p0.y) : 0.0f;
                    float w1 = l1 ? __int_as_float(p1.y) : 0.0f;
                    float w2 = l2 ? __int_as_float(p2.y) : 0.0f;
                    float w3 = l3 ? __int_as_float(p3.y) : 0.0f;
                    ax += w0 * __uint_as_float(g0.x << 16);
                    ay += w0 * __uint_as_float(g0.x & 0xFFFF0000u);
                    az += w0 * __uint_as_float(g0.y << 16);
                    aw += w0 * __uint_as_float(g0.y & 0xFFFF0000u);
                    ax += w1 * __uint_as_float(g1.x << 16);
                    ay += w1 * __uint_as_float(g1.x & 0xFFFF0000u);
                    az += w1 * __uint_as_float(g1.y << 16);
                    aw += w1 * __uint_as_float(g1.y & 0xFFFF0000u);
                    ax += w2 * __uint_as_float(g2.x << 16);
                    ay += w2 * __uint_as_float(g2.x & 0xFFFF0000u);
                    az += w2 * __uint_as_float(g2.y << 16);
                    aw += w2 * __uint_as_float(g2.y & 0xFFFF0000u);
                    ax += w3 * __uint_as_float(g3.x << 16);
                    ay += w3 * __uint_as_float(g3.x & 0xFFFF0000u);
                    az += w3 * __uint_as_float(g3.y << 16);
                    aw += w3 * __uint_as_float(g3.y & 0xFFFF0000u);
                }
            }
            ax += __shfl_xor(ax, 16); ay += __shfl_xor(ay, 16);
            az += __shfl_xor(az, 16); aw += __shfl_xor(aw, 16);
            ax += __shfl_xor(ax, 32); ay += __shfl_xor(ay, 32);
            az += __shfl_xor(az, 32); aw += __shfl_xor(aw, 32);
            if (grp == 0) {
                ushort4 pk;
                pk.x = f2bf(hv.x + ax); pk.y = f2bf(hv.y + ay);
                pk.z = f2bf(hv.z + az); pk.w = f2bf(hv.w + aw);
                *(ushort4*)(sX + (wid * 16 + t) * PITCH_HID + sub * 4) = pk;
            }
        } else if (grp == 0) {
            ushort4 z; z.x = 0; z.y = 0; z.z = 0; z.w = 0;
            *(ushort4*)(sX + (wid * 16 + t) * PITCH_HID + sub * 4) = z;
        }
    }
    __syncthreads();

    // ---- Phase 2: 16x16x32 bf16 MFMA (K=64) + relu epilogue ----
    const int l16 = lane & 15;
    const int q   = lane >> 4;

    f32x4 acc[4] = {{0,0,0,0},{0,0,0,0},{0,0,0,0},{0,0,0,0}};
    const bf16x8* wf8 = (const bf16x8*)wf;

    #pragma unroll
    for (int kc = 0; kc < 2; ++kc) {
        bf16x8 af = *(const bf16x8*)(sX + (wid * 16 + l16) * PITCH_HID + kc * 32 + q * 8);
        #pragma unroll
        for (int nt = 0; nt < 4; ++nt) {
            bf16x8 bfr = wf8[((kc * 4 + nt) * 4 + q) * 16 + l16];
            acc[nt] = __builtin_amdgcn_mfma_f32_16x16x32_bf16(af, bfr, acc[nt], 0, 0, 0);
        }
    }

    #pragma unroll
    for (int nt = 0; nt < 4; ++nt) {
        float bb = b[nt * 16 + l16];
        #pragma unroll
        for (int reg = 0; reg < 4; ++reg) {
            int rg = row0 + wid * 16 + q * 4 + reg;
            if (rg < N_NODES) {
                float v = fmaxf(acc[nt][reg] + bb, 0.0f);
                hnext[(size_t)rg * HID + nt * 16 + l16] = v;
                if (store_bf)
                    hbf_out[(size_t)rg * HID + nt * 16 + l16] = __float2bfloat16(v);
            }
        }
    }
}

extern "C" void kernel_launch(void* const* d_in, const int* in_sizes, int n_in,
                              void* d_out, int out_size, void* d_ws, size_t ws_size,
                              hipStream_t stream) {
    const float* x   = (const float*)d_in[0];
    const int*   ei  = (const int*)  d_in[1];   // (2, E): [src | tgt]
    const float* ea  = (const float*)d_in[2];
    const float* Wi  = (const float*)d_in[3];
    const float* bi  = (const float*)d_in[4];
    const float* W1  = (const float*)d_in[5];
    const float* b1  = (const float*)d_in[6];
    const float* W2  = (const float*)d_in[7];
    const float* b2  = (const float*)d_in[8];
    const float* W3  = (const float*)d_in[9];
    const float* b3  = (const float*)d_in[10];
    const float* bl[3] = { b1, b2, b3 };
    float* out = (float*)d_out;  // (4, N, HID)

    const int* src = ei;
    const int* tgt = ei + N_EDGES;

    // Workspace layout (hbf double-buffered).
    unsigned long long* binned = (unsigned long long*)d_ws;          // E * 8B
    int* offs         = (int*)(binned + N_EDGES);
    int* counts       = offs + N_NODES;
    int* g_bin_cnt    = counts + N_NODES;
    int* g_bin_offs   = g_bin_cnt + NBINS;
    int* g_bin_cursor = g_bin_offs + NBINS;
    int* pad          = g_bin_cursor + NBINS;                        // keep 8B align
    unsigned long long* pairs = (unsigned long long*)(pad + 1);      // E * 8B
    __hip_bfloat16* hbf0 = (__hip_bfloat16*)(pairs + N_EDGES);       // N*HID bf16
    __hip_bfloat16* hbf1 = hbf0 + (size_t)N_NODES * HID;             // N*HID bf16
    unsigned short* wf_in  = (unsigned short*)(hbf1 + (size_t)N_NODES * HID);
    unsigned short* wf_hid = wf_in + 8192;                           // 3 x 4096

    hipMemsetAsync(g_bin_cnt, 0, NBINS * sizeof(int), stream);

    wf_prep_kernel<<<32, 256, 0, stream>>>(Wi, W1, W2, W3, wf_in, wf_hid);

    const int eb_blocks = (N_EDGES + EB - 1) / EB;  // 782
    bin_hist_kernel   <<<eb_blocks, 256, 0, stream>>>(tgt, g_bin_cnt);
    bin_scan_kernel   <<<1, 512, 0, stream>>>(g_bin_cnt, g_bin_offs, g_bin_cursor);
    bin_scatter_kernel<<<eb_blocks, 256, 0, stream>>>(src, tgt, ea, g_bin_cursor, binned);
    fine_fill_kernel  <<<NBINS, 1024, 0, stream>>>(binned, g_bin_offs, g_bin_cnt,
                                                   offs, counts, pairs);

    const int gemm_blocks = (N_NODES + 63) / 64;  // 1563
    gemm_in_kernel<<<gemm_blocks, 256, 0, stream>>>(x, wf_in, bi, out, hbf0);

    __hip_bfloat16* hin  = hbf0;
    __hip_bfloat16* hout = hbf1;
    for (int l = 0; l < 3; ++l) {
        const float* hl = out + (size_t)l * N_NODES * HID;
        float* hn       = out + (size_t)(l + 1) * N_NODES * HID;
        agg_gemm_kernel<<<gemm_blocks, 256, 0, stream>>>(
            hl, hin, offs, counts, (const int2*)pairs,
            wf_hid + (size_t)l * 4096, bl[l], hn, hout, (l < 2) ? 1 : 0);
        __hip_bfloat16* t = hin; hin = hout; hout = t;
    }
}

// Round 3
// 441.479 us; speedup vs baseline: 1.0869x; 1.0869x over previous
//
#include <hip/hip_runtime.h>
#include <hip/hip_bf16.h>

#define N_NODES 100000
#define N_EDGES 1600000
#define IN_DIM  128
#define HID     64
#define BIN_NODES 256
#define NBINS   ((N_NODES + BIN_NODES - 1) / BIN_NODES)   // 391
#define EB      2048       // edges per block in bin_hist / bin_scatter

#define PITCH_IN  152      // bf16 units per LDS row for K=128 (+24 pad: 2-way banks, 16B-aligned)
#define PITCH_HID 88       // bf16 units per LDS row for K=64  (+24 pad)

typedef __attribute__((ext_vector_type(8))) short bf16x8;   // MFMA A/B frag (4 VGPRs)
typedef __attribute__((ext_vector_type(4))) float f32x4;    // MFMA C/D frag

__device__ inline unsigned short f2bf(float f) {
    __hip_bfloat16 b = __float2bfloat16(f);
    return *reinterpret_cast<unsigned short*>(&b);
}

// ---------------------------------------------------------------------------
// Pre-pack W matrices into B-fragment order bf16:
// flat = (((kc*4 + nt)*4 + quad)*16 + n16)*8 + j ;  k = kc*32+quad*8+j, n = nt*16+n16
// ---------------------------------------------------------------------------
__global__ void wf_prep_kernel(const float* __restrict__ Wi,
                               const float* __restrict__ W1,
                               const float* __restrict__ W2,
                               const float* __restrict__ W3,
                               unsigned short* __restrict__ wf_in,
                               unsigned short* __restrict__ wf_hid) {
    int t = blockIdx.x * 256 + threadIdx.x;
    if (t < 8192) {  // Wi: K=128 -> kc in 0..3
        int j = t & 7, n16 = (t >> 3) & 15, quad = (t >> 7) & 3, nt = (t >> 9) & 3, kc = t >> 11;
        int k = kc * 32 + quad * 8 + j, n = nt * 16 + n16;
        wf_in[t] = f2bf(Wi[k * HID + n]);
    }
    if (t < 4096) {  // W1..W3: K=64 -> kc in 0..1
        int j = t & 7, n16 = (t >> 3) & 15, quad = (t >> 7) & 3, nt = (t >> 9) & 3, kc = t >> 11;
        int k = kc * 32 + quad * 8 + j, n = nt * 16 + n16;
        wf_hid[t]        = f2bf(W1[k * HID + n]);
        wf_hid[4096 + t] = f2bf(W2[k * HID + n]);
        wf_hid[8192 + t] = f2bf(W3[k * HID + n]);
    }
}

// ---------------------------------------------------------------------------
// h0 = relu(x @ Wi + bi) via bf16 MFMA. Block = 64 rows, wave = 16 rows.
// ---------------------------------------------------------------------------
__global__ __launch_bounds__(256) void gemm_in_kernel(
        const float* __restrict__ x,
        const unsigned short* __restrict__ wf,   // fragment-order Wi (bf16 bits)
        const float* __restrict__ bi,
        float* __restrict__ h0,
        __hip_bfloat16* __restrict__ hbf) {
    __shared__ unsigned short sX[64 * PITCH_IN];   // 19456 B
    const int tid  = threadIdx.x;
    const int row0 = blockIdx.x * 64;

    // Stage x tile (64 x 128 f32 -> bf16), coalesced float4 reads, 8B LDS writes.
    #pragma unroll
    for (int it = 0; it < 8; ++it) {
        int i  = tid + it * 256;
        int r  = i >> 5;        // 32 float4 per row
        int kq = i & 31;
        int rg = row0 + r;
        float4 v = (rg < N_NODES)
                 ? ((const float4*)x)[(size_t)rg * (IN_DIM / 4) + kq]
                 : make_float4(0.f, 0.f, 0.f, 0.f);
        ushort4 pk;
        pk.x = f2bf(v.x); pk.y = f2bf(v.y); pk.z = f2bf(v.z); pk.w = f2bf(v.w);
        *(ushort4*)(sX + r * PITCH_IN + kq * 4) = pk;
    }
    __syncthreads();

    const int lane = tid & 63;
    const int wid  = tid >> 6;
    const int l16  = lane & 15;
    const int q    = lane >> 4;

    f32x4 acc[4] = {{0,0,0,0},{0,0,0,0},{0,0,0,0},{0,0,0,0}};
    const bf16x8* wf8 = (const bf16x8*)wf;

    #pragma unroll
    for (int kc = 0; kc < 4; ++kc) {
        bf16x8 af = *(const bf16x8*)(sX + (wid * 16 + l16) * PITCH_IN + kc * 32 + q * 8);
        #pragma unroll
        for (int nt = 0; nt < 4; ++nt) {
            bf16x8 bfr = wf8[((kc * 4 + nt) * 4 + q) * 16 + l16];
            acc[nt] = __builtin_amdgcn_mfma_f32_16x16x32_bf16(af, bfr, acc[nt], 0, 0, 0);
        }
    }

    // Epilogue: C/D layout col = lane&15, row = quad*4 + reg  [m89]
    #pragma unroll
    for (int nt = 0; nt < 4; ++nt) {
        float bb = bi[nt * 16 + l16];
        #pragma unroll
        for (int reg = 0; reg < 4; ++reg) {
            int rg = row0 + wid * 16 + q * 4 + reg;
            if (rg < N_NODES) {
                float v = fmaxf(acc[nt][reg] + bb, 0.0f);
                h0 [(size_t)rg * HID + nt * 16 + l16] = v;
                hbf[(size_t)rg * HID + nt * 16 + l16] = __float2bfloat16(v);
            }
        }
    }
}

// ---------------------------------------------------------------------------
// Binned CSR build.  Record: high32 = w bits, low32 = (local_tgt<<17) | src.
// ---------------------------------------------------------------------------
__global__ void bin_hist_kernel(const int* __restrict__ tgt,
                                int* __restrict__ g_bin_cnt) {
    __shared__ int cnt[NBINS];
    for (int i = threadIdx.x; i < NBINS; i += 256) cnt[i] = 0;
    __syncthreads();
    const int e0 = blockIdx.x * EB;
    for (int i = threadIdx.x; i < EB; i += 256) {
        int e = e0 + i;
        if (e < N_EDGES) atomicAdd(&cnt[tgt[e] >> 8], 1);
    }
    __syncthreads();
    for (int i = threadIdx.x; i < NBINS; i += 256)
        if (cnt[i]) atomicAdd(&g_bin_cnt[i], cnt[i]);
}

__global__ void bin_scan_kernel(const int* __restrict__ g_bin_cnt,
                                int* __restrict__ g_bin_offs,
                                int* __restrict__ g_bin_cursor) {
    __shared__ int s[512];
    const int tid = threadIdx.x;
    int v = (tid < NBINS) ? g_bin_cnt[tid] : 0;
    s[tid] = v;
    __syncthreads();
    for (int off = 1; off < 512; off <<= 1) {
        int t = (tid >= off) ? s[tid - off] : 0;
        __syncthreads();
        s[tid] += t;
        __syncthreads();
    }
    if (tid < NBINS) { g_bin_offs[tid] = s[tid] - v; g_bin_cursor[tid] = s[tid] - v; }
}

__global__ void bin_scatter_kernel(const int* __restrict__ src,
                                   const int* __restrict__ tgt,
                                   const float* __restrict__ ea,
                                   int* __restrict__ g_bin_cursor,
                                   unsigned long long* __restrict__ binned) {
    __shared__ int cnt[NBINS];
    __shared__ int base[NBINS];
    __shared__ int cur[NBINS];
    for (int i = threadIdx.x; i < NBINS; i += 256) cnt[i] = 0;
    __syncthreads();

    const int e0 = blockIdx.x * EB;
    int myb[EB / 256];
    unsigned long long myrec[EB / 256];
    #pragma unroll
    for (int i = 0; i < EB / 256; ++i) {
        int e = e0 + threadIdx.x + i * 256;
        if (e < N_EDGES) {
            int t = tgt[e];
            int b = t >> 8;
            myb[i] = b;
            myrec[i] = ((unsigned long long)(unsigned)__float_as_int(ea[e]) << 32)
                     | ((unsigned)(t & 255) << 17) | (unsigned)src[e];
            atomicAdd(&cnt[b], 1);
        } else {
            myb[i] = -1;
        }
    }
    __syncthreads();
    for (int i = threadIdx.x; i < NBINS; i += 256) {
        cur[i]  = 0;
        base[i] = cnt[i] ? atomicAdd(&g_bin_cursor[i], cnt[i]) : 0;
    }
    __syncthreads();
    #pragma unroll
    for (int i = 0; i < EB / 256; ++i) {
        if (myb[i] >= 0) {
            int r = atomicAdd(&cur[myb[i]], 1);
            binned[base[myb[i]] + r] = myrec[i];
        }
    }
}

// 1024 threads/block: 391 blocks is only ~1.5 blocks/CU, so widen each block
// to 16 waves to restore occupancy for the two edge-sweep loops.
__global__ __launch_bounds__(1024) void fine_fill_kernel(
                                 const unsigned long long* __restrict__ binned,
                                 const int* __restrict__ g_bin_offs,
                                 const int* __restrict__ g_bin_cnt,
                                 int* __restrict__ offs,
                                 int* __restrict__ counts,
                                 unsigned long long* __restrict__ pairs) {
    __shared__ int ncnt[256];
    __shared__ int nbase[256];
    __shared__ int wsum[4];
    const int b    = blockIdx.x;
    const int tid  = threadIdx.x;
    const int ebeg = g_bin_offs[b];
    const int ecnt = g_bin_cnt[b];

    if (tid < 256) ncnt[tid] = 0;
    __syncthreads();
    for (int i = tid; i < ecnt; i += 1024) {
        int lt = (int)((binned[ebeg + i] >> 17) & 255);
        atomicAdd(&ncnt[lt], 1);
    }
    __syncthreads();

    if (tid < 256) {   // wave-uniform guard: waves 0-3 only
        const int lane = tid & 63, wid = tid >> 6;
        int v  = ncnt[tid];
        int sc = v;
        #pragma unroll
        for (int d = 1; d < 64; d <<= 1) {
            int t = __shfl_up(sc, d);
            if (lane >= d) sc += t;
        }
        if (lane == 63) wsum[wid] = sc;
        __syncthreads();
        int wb = 0;
        for (int w = 0; w < wid; ++w) wb += wsum[w];
        int excl = wb + sc - v;
        nbase[tid] = excl;

        const int node = b * BIN_NODES + tid;
        if (node < N_NODES) { offs[node] = ebeg + excl; counts[node] = v; }

        ncnt[tid] = 0;  // reuse as cursor
    } else {
        __syncthreads();
    }
    __syncthreads();
    for (int i = tid; i < ecnt; i += 1024) {
        unsigned long long rec = binned[ebeg + i];
        int lt = (int)((rec >> 17) & 255);
        int r  = atomicAdd(&ncnt[lt], 1);
        pairs[ebeg + nbase[lt] + r] =
            (rec & 0xFFFFFFFF00000000ull) | (rec & 0x1FFFFull);
    }
}

// ---------------------------------------------------------------------------
// FUSED: a = h + segment_sum(bf16(h)[src] * w) ; hnext = relu(a @ W + b).
// Phase 1 (latency-bound gather) change vs R1: the per-edge (src,w) pair is
// no longer a dependent load ahead of the row gather. The whole wave prefetches
// up to 64 sequential pairs in ONE coalesced load (pairs[beg+lane]); groups
// pick their edge's pair via __shfl (VALU). The gather loop's memory chain is
// then a single level of independent hbf row loads.
// ---------------------------------------------------------------------------
__global__ __launch_bounds__(256) void agg_gemm_kernel(
        const float* __restrict__ h,               // layer-l activations (f32)
        const __hip_bfloat16* __restrict__ hbf_in, // layer-l activations (bf16)
        const int* __restrict__ offs,
        const int* __restrict__ counts,
        const int2* __restrict__ pairs,
        const unsigned short* __restrict__ wf,     // fragment-order W (bf16 bits)
        const float* __restrict__ b,
        float* __restrict__ hnext,
        __hip_bfloat16* __restrict__ hbf_out,
        const int store_bf) {
    __shared__ unsigned short sX[64 * PITCH_HID];  // 11264 B
    const int tid  = threadIdx.x;
    const int row0 = blockIdx.x * 64;
    const int lane = tid & 63;
    const int wid  = tid >> 6;
    const int grp  = lane >> 4;
    const int sub  = lane & 15;

    // ---- Phase 1: aggregate 16 nodes per wave into LDS (bf16) ----
    for (int t = 0; t < 16; ++t) {
        const int node = row0 + wid * 16 + t;      // wave-uniform
        if (node < N_NODES) {
            const int beg = offs[node];
            const int cnt = counts[node];
            float ax = 0.f, ay = 0.f, az = 0.f, aw = 0.f;
            for (int j0 = 0; j0 < cnt; j0 += 64) {
                // Coalesced wave-wide pair prefetch (clamped in-bounds).
                int idx = beg + j0 + lane;
                int2 pl = pairs[min(idx, N_EDGES - 1)];
                const int nb   = min(64, cnt - j0);
                const int last = nb - 1;
                for (int i = 0; i < nb; i += 8) {
                    int e0 = i + grp;
                    int e1 = i + 4 + grp;
                    bool l0 = (e0 <= last);
                    bool l1 = (e1 <= last);
                    int s0 = __shfl(pl.x, l0 ? e0 : last);
                    int w0i = __shfl(pl.y, l0 ? e0 : last);
                    int s1 = __shfl(pl.x, l1 ? e1 : last);
                    int w1i = __shfl(pl.y, l1 ? e1 : last);
                    uint2 g0 = *(const uint2*)(hbf_in + (size_t)s0 * HID + sub * 4);
                    uint2 g1 = *(const uint2*)(hbf_in + (size_t)s1 * HID + sub * 4);
                    float w0 = l0 ? __int_as_float(w0i) : 0.0f;
                    float w1 = l1 ? __int_as_float(w1i) : 0.0f;
                    ax += w0 * __uint_as_float(g0.x << 16);
                    ay += w0 * __uint_as_float(g0.x & 0xFFFF0000u);
                    az += w0 * __uint_as_float(g0.y << 16);
                    aw += w0 * __uint_as_float(g0.y & 0xFFFF0000u);
                    ax += w1 * __uint_as_float(g1.x << 16);
                    ay += w1 * __uint_as_float(g1.x & 0xFFFF0000u);
                    az += w1 * __uint_as_float(g1.y << 16);
                    aw += w1 * __uint_as_float(g1.y & 0xFFFF0000u);
                }
            }
            ax += __shfl_xor(ax, 16); ay += __shfl_xor(ay, 16);
            az += __shfl_xor(az, 16); aw += __shfl_xor(aw, 16);
            ax += __shfl_xor(ax, 32); ay += __shfl_xor(ay, 32);
            az += __shfl_xor(az, 32); aw += __shfl_xor(aw, 32);
            if (grp == 0) {
                const float4 hv = *(const float4*)(h + (size_t)node * HID + sub * 4);
                ushort4 pk;
                pk.x = f2bf(hv.x + ax); pk.y = f2bf(hv.y + ay);
                pk.z = f2bf(hv.z + az); pk.w = f2bf(hv.w + aw);
                *(ushort4*)(sX + (wid * 16 + t) * PITCH_HID + sub * 4) = pk;
            }
        } else if (grp == 0) {
            ushort4 z; z.x = 0; z.y = 0; z.z = 0; z.w = 0;
            *(ushort4*)(sX + (wid * 16 + t) * PITCH_HID + sub * 4) = z;
        }
    }
    __syncthreads();

    // ---- Phase 2: 16x16x32 bf16 MFMA (K=64) + relu epilogue ----
    const int l16 = lane & 15;
    const int q   = lane >> 4;

    f32x4 acc[4] = {{0,0,0,0},{0,0,0,0},{0,0,0,0},{0,0,0,0}};
    const bf16x8* wf8 = (const bf16x8*)wf;

    #pragma unroll
    for (int kc = 0; kc < 2; ++kc) {
        bf16x8 af = *(const bf16x8*)(sX + (wid * 16 + l16) * PITCH_HID + kc * 32 + q * 8);
        #pragma unroll
        for (int nt = 0; nt < 4; ++nt) {
            bf16x8 bfr = wf8[((kc * 4 + nt) * 4 + q) * 16 + l16];
            acc[nt] = __builtin_amdgcn_mfma_f32_16x16x32_bf16(af, bfr, acc[nt], 0, 0, 0);
        }
    }

    #pragma unroll
    for (int nt = 0; nt < 4; ++nt) {
        float bb = b[nt * 16 + l16];
        #pragma unroll
        for (int reg = 0; reg < 4; ++reg) {
            int rg = row0 + wid * 16 + q * 4 + reg;
            if (rg < N_NODES) {
                float v = fmaxf(acc[nt][reg] + bb, 0.0f);
                hnext[(size_t)rg * HID + nt * 16 + l16] = v;
                if (store_bf)
                    hbf_out[(size_t)rg * HID + nt * 16 + l16] = __float2bfloat16(v);
            }
        }
    }
}

extern "C" void kernel_launch(void* const* d_in, const int* in_sizes, int n_in,
                              void* d_out, int out_size, void* d_ws, size_t ws_size,
                              hipStream_t stream) {
    const float* x   = (const float*)d_in[0];
    const int*   ei  = (const int*)  d_in[1];   // (2, E): [src | tgt]
    const float* ea  = (const float*)d_in[2];
    const float* Wi  = (const float*)d_in[3];
    const float* bi  = (const float*)d_in[4];
    const float* W1  = (const float*)d_in[5];
    const float* b1  = (const float*)d_in[6];
    const float* W2  = (const float*)d_in[7];
    const float* b2  = (const float*)d_in[8];
    const float* W3  = (const float*)d_in[9];
    const float* b3  = (const float*)d_in[10];
    const float* bl[3] = { b1, b2, b3 };
    float* out = (float*)d_out;  // (4, N, HID)

    const int* src = ei;
    const int* tgt = ei + N_EDGES;

    // Workspace layout (hbf double-buffered).
    unsigned long long* binned = (unsigned long long*)d_ws;          // E * 8B
    int* offs         = (int*)(binned + N_EDGES);
    int* counts       = offs + N_NODES;
    int* g_bin_cnt    = counts + N_NODES;
    int* g_bin_offs   = g_bin_cnt + NBINS;
    int* g_bin_cursor = g_bin_offs + NBINS;
    int* pad          = g_bin_cursor + NBINS;                        // keep 8B align
    unsigned long long* pairs = (unsigned long long*)(pad + 1);      // E * 8B
    __hip_bfloat16* hbf0 = (__hip_bfloat16*)(pairs + N_EDGES);       // N*HID bf16
    __hip_bfloat16* hbf1 = hbf0 + (size_t)N_NODES * HID;             // N*HID bf16
    unsigned short* wf_in  = (unsigned short*)(hbf1 + (size_t)N_NODES * HID);
    unsigned short* wf_hid = wf_in + 8192;                           // 3 x 4096

    hipMemsetAsync(g_bin_cnt, 0, NBINS * sizeof(int), stream);

    wf_prep_kernel<<<32, 256, 0, stream>>>(Wi, W1, W2, W3, wf_in, wf_hid);

    const int eb_blocks = (N_EDGES + EB - 1) / EB;  // 782
    bin_hist_kernel   <<<eb_blocks, 256, 0, stream>>>(tgt, g_bin_cnt);
    bin_scan_kernel   <<<1, 512, 0, stream>>>(g_bin_cnt, g_bin_offs, g_bin_cursor);
    bin_scatter_kernel<<<eb_blocks, 256, 0, stream>>>(src, tgt, ea, g_bin_cursor, binned);
    fine_fill_kernel  <<<NBINS, 1024, 0, stream>>>(binned, g_bin_offs, g_bin_cnt,
                                                   offs, counts, pairs);

    const int gemm_blocks = (N_NODES + 63) / 64;  // 1563
    gemm_in_kernel<<<gemm_blocks, 256, 0, stream>>>(x, wf_in, bi, out, hbf0);

    __hip_bfloat16* hin  = hbf0;
    __hip_bfloat16* hout = hbf1;
    for (int l = 0; l < 3; ++l) {
        const float* hl = out + (size_t)l * N_NODES * HID;
        float* hn       = out + (size_t)(l + 1) * N_NODES * HID;
        agg_gemm_kernel<<<gemm_blocks, 256, 0, stream>>>(
            hl, hin, offs, counts, (const int2*)pairs,
            wf_hid + (size_t)l * 4096, bl[l], hn, hout, (l < 2) ? 1 : 0);
        __hip_bfloat16* t = hin; hin = hout; hout = t;
    }
}

// Round 4
// 397.357 us; speedup vs baseline: 1.2076x; 1.1110x over previous
//
#include <hip/hip_runtime.h>
#include <hip/hip_bf16.h>

#define N_NODES 100000
#define N_EDGES 1600000
#define IN_DIM  128
#define HID     64
#define BIN_NODES 256
#define NBINS   ((N_NODES + BIN_NODES - 1) / BIN_NODES)   // 391
#define EB      2048       // edges per block in scatter_sort
#define CAP     8192       // padded per-bin capacity (avg fill 4096, sigma~64)
#define PAIRS_LIM (NBINS * CAP - 1)

#define PITCH_IN  152      // bf16 units per LDS row for K=128 (+24 pad: 2-way banks, 16B-aligned)
#define PITCH_HID 88       // bf16 units per LDS row for K=64  (+24 pad)

typedef __attribute__((ext_vector_type(8))) short bf16x8;   // MFMA A/B frag (4 VGPRs)
typedef __attribute__((ext_vector_type(4))) float f32x4;    // MFMA C/D frag

__device__ inline unsigned short f2bf(float f) {
    __hip_bfloat16 b = __float2bfloat16(f);
    return *reinterpret_cast<unsigned short*>(&b);
}

// ---------------------------------------------------------------------------
// Pre-pack W matrices into B-fragment order bf16 + init padded-bin cursors.
// flat = (((kc*4 + nt)*4 + quad)*16 + n16)*8 + j ;  k = kc*32+quad*8+j, n = nt*16+n16
// ---------------------------------------------------------------------------
__global__ void wf_prep_kernel(const float* __restrict__ Wi,
                               const float* __restrict__ W1,
                               const float* __restrict__ W2,
                               const float* __restrict__ W3,
                               unsigned short* __restrict__ wf_in,
                               unsigned short* __restrict__ wf_hid,
                               int* __restrict__ g_bin_cursor) {
    int t = blockIdx.x * 256 + threadIdx.x;
    if (t < NBINS) g_bin_cursor[t] = t * CAP;
    if (t < 8192) {  // Wi: K=128 -> kc in 0..3
        int j = t & 7, n16 = (t >> 3) & 15, quad = (t >> 7) & 3, nt = (t >> 9) & 3, kc = t >> 11;
        int k = kc * 32 + quad * 8 + j, n = nt * 16 + n16;
        wf_in[t] = f2bf(Wi[k * HID + n]);
    }
    if (t < 4096) {  // W1..W3: K=64 -> kc in 0..1
        int j = t & 7, n16 = (t >> 3) & 15, quad = (t >> 7) & 3, nt = (t >> 9) & 3, kc = t >> 11;
        int k = kc * 32 + quad * 8 + j, n = nt * 16 + n16;
        wf_hid[t]        = f2bf(W1[k * HID + n]);
        wf_hid[4096 + t] = f2bf(W2[k * HID + n]);
        wf_hid[8192 + t] = f2bf(W3[k * HID + n]);
    }
}

// ---------------------------------------------------------------------------
// h0 = relu(x @ Wi + bi) via bf16 MFMA. Block = 64 rows, wave = 16 rows.
// ---------------------------------------------------------------------------
__global__ __launch_bounds__(256) void gemm_in_kernel(
        const float* __restrict__ x,
        const unsigned short* __restrict__ wf,   // fragment-order Wi (bf16 bits)
        const float* __restrict__ bi,
        float* __restrict__ h0,
        __hip_bfloat16* __restrict__ hbf) {
    __shared__ unsigned short sX[64 * PITCH_IN];   // 19456 B
    const int tid  = threadIdx.x;
    const int row0 = blockIdx.x * 64;

    // Stage x tile (64 x 128 f32 -> bf16), coalesced float4 reads, 8B LDS writes.
    #pragma unroll
    for (int it = 0; it < 8; ++it) {
        int i  = tid + it * 256;
        int r  = i >> 5;        // 32 float4 per row
        int kq = i & 31;
        int rg = row0 + r;
        float4 v = (rg < N_NODES)
                 ? ((const float4*)x)[(size_t)rg * (IN_DIM / 4) + kq]
                 : make_float4(0.f, 0.f, 0.f, 0.f);
        ushort4 pk;
        pk.x = f2bf(v.x); pk.y = f2bf(v.y); pk.z = f2bf(v.z); pk.w = f2bf(v.w);
        *(ushort4*)(sX + r * PITCH_IN + kq * 4) = pk;
    }
    __syncthreads();

    const int lane = tid & 63;
    const int wid  = tid >> 6;
    const int l16  = lane & 15;
    const int q    = lane >> 4;

    f32x4 acc[4] = {{0,0,0,0},{0,0,0,0},{0,0,0,0},{0,0,0,0}};
    const bf16x8* wf8 = (const bf16x8*)wf;

    #pragma unroll
    for (int kc = 0; kc < 4; ++kc) {
        bf16x8 af = *(const bf16x8*)(sX + (wid * 16 + l16) * PITCH_IN + kc * 32 + q * 8);
        #pragma unroll
        for (int nt = 0; nt < 4; ++nt) {
            bf16x8 bfr = wf8[((kc * 4 + nt) * 4 + q) * 16 + l16];
            acc[nt] = __builtin_amdgcn_mfma_f32_16x16x32_bf16(af, bfr, acc[nt], 0, 0, 0);
        }
    }

    // Epilogue: C/D layout col = lane&15, row = quad*4 + reg  [m89]
    #pragma unroll
    for (int nt = 0; nt < 4; ++nt) {
        float bb = bi[nt * 16 + l16];
        #pragma unroll
        for (int reg = 0; reg < 4; ++reg) {
            int rg = row0 + wid * 16 + q * 4 + reg;
            if (rg < N_NODES) {
                float v = fmaxf(acc[nt][reg] + bb, 0.0f);
                h0 [(size_t)rg * HID + nt * 16 + l16] = v;
                hbf[(size_t)rg * HID + nt * 16 + l16] = __float2bfloat16(v);
            }
        }
    }
}

// ---------------------------------------------------------------------------
// One-pass binned CSR scatter with LDS sort for coalesced output.
// Record: high32 = w bits, low32 = (local_tgt<<17) | src.
// Bins are PADDED (bin b occupies [b*CAP, b*CAP+cnt_b)); g_bin_cursor was
// pre-initialized to b*CAP, so no hist/scan passes are needed.
// Output writes are in bin-sorted LDS order: consecutive lanes write runs of
// consecutive addresses (~5 per bin) instead of 64 fully-scattered 8B stores.
// ---------------------------------------------------------------------------
__global__ __launch_bounds__(256) void scatter_sort_kernel(
        const int* __restrict__ src,
        const int* __restrict__ tgt,
        const float* __restrict__ ea,
        int* __restrict__ g_bin_cursor,
        unsigned long long* __restrict__ binned) {
    __shared__ int cnt[NBINS];
    __shared__ int lstart[NBINS];
    __shared__ int lbase[NBINS];
    __shared__ int cur[NBINS];
    __shared__ unsigned long long srec[EB];   // 16 KB
    __shared__ unsigned short sbin[EB];       // 4 KB
    __shared__ int stot;
    const int tid = threadIdx.x;

    for (int i = tid; i < NBINS; i += 256) { cnt[i] = 0; cur[i] = 0; }
    __syncthreads();

    const int e0 = blockIdx.x * EB;
    int myb[EB / 256];
    unsigned long long myrec[EB / 256];
    #pragma unroll
    for (int i = 0; i < EB / 256; ++i) {
        int e = e0 + tid + i * 256;
        if (e < N_EDGES) {
            int t = tgt[e];
            int b = t >> 8;
            myb[i] = b;
            myrec[i] = ((unsigned long long)(unsigned)__float_as_int(ea[e]) << 32)
                     | ((unsigned)(t & 255) << 17) | (unsigned)src[e];
            atomicAdd(&cnt[b], 1);
        } else {
            myb[i] = -1;
        }
    }
    __syncthreads();

    // Wave 0: ripple exclusive scan of cnt[0..NBINS) -> lstart
    if (tid < 64) {
        int carry = 0;
        for (int c = 0; c < (NBINS + 63) / 64; ++c) {
            int idx = c * 64 + tid;
            int v = (idx < NBINS) ? cnt[idx] : 0;
            int sc = v;
            #pragma unroll
            for (int d = 1; d < 64; d <<= 1) {
                int t2 = __shfl_up(sc, d);
                if (tid >= d) sc += t2;
            }
            if (idx < NBINS) lstart[idx] = carry + sc - v;
            carry += __shfl(sc, 63);
        }
        if (tid == 0) stot = carry;
    }
    __syncthreads();

    // One global atomic per touched bin for this block's base.
    for (int i = tid; i < NBINS; i += 256)
        if (cnt[i]) lbase[i] = atomicAdd(&g_bin_cursor[i], cnt[i]);
    __syncthreads();

    // Local scatter into bin-sorted LDS order.
    #pragma unroll
    for (int i = 0; i < EB / 256; ++i) {
        if (myb[i] >= 0) {
            int r = atomicAdd(&cur[myb[i]], 1);
            int p = lstart[myb[i]] + r;
            srec[p] = myrec[i];
            sbin[p] = (unsigned short)myb[i];
        }
    }
    __syncthreads();

    // Coalesced-ish output: sorted order -> per-bin contiguous runs.
    const int tot = stot;
    for (int i = tid; i < tot; i += 256) {
        int b = sbin[i];
        binned[(size_t)lbase[b] + (i - lstart[b])] = srec[i];
    }
}

// 1024 threads/block: 391 blocks is only ~1.5 blocks/CU, so widen each block
// to 16 waves to restore occupancy for the two edge-sweep loops.
__global__ __launch_bounds__(1024) void fine_fill_kernel(
                                 const unsigned long long* __restrict__ binned,
                                 const int* __restrict__ g_bin_cursor,
                                 int* __restrict__ offs,
                                 int* __restrict__ counts,
                                 unsigned long long* __restrict__ pairs) {
    __shared__ int ncnt[256];
    __shared__ int nbase[256];
    __shared__ int wsum[4];
    const int b    = blockIdx.x;
    const int tid  = threadIdx.x;
    const int ebeg = b * CAP;
    const int ecnt = g_bin_cursor[b] - ebeg;

    if (tid < 256) ncnt[tid] = 0;
    __syncthreads();
    for (int i = tid; i < ecnt; i += 1024) {
        int lt = (int)((binned[ebeg + i] >> 17) & 255);
        atomicAdd(&ncnt[lt], 1);
    }
    __syncthreads();

    if (tid < 256) {   // wave-uniform guard: waves 0-3 only
        const int lane = tid & 63, wid = tid >> 6;
        int v  = ncnt[tid];
        int sc = v;
        #pragma unroll
        for (int d = 1; d < 64; d <<= 1) {
            int t = __shfl_up(sc, d);
            if (lane >= d) sc += t;
        }
        if (lane == 63) wsum[wid] = sc;
        __syncthreads();
        int wb = 0;
        for (int w = 0; w < wid; ++w) wb += wsum[w];
        int excl = wb + sc - v;
        nbase[tid] = excl;

        const int node = b * BIN_NODES + tid;
        if (node < N_NODES) { offs[node] = ebeg + excl; counts[node] = v; }

        ncnt[tid] = 0;  // reuse as cursor
    } else {
        __syncthreads();
    }
    __syncthreads();
    for (int i = tid; i < ecnt; i += 1024) {
        unsigned long long rec = binned[ebeg + i];
        int lt = (int)((rec >> 17) & 255);
        int r  = atomicAdd(&ncnt[lt], 1);
        pairs[ebeg + nbase[lt] + r] =
            (rec & 0xFFFFFFFF00000000ull) | (rec & 0x1FFFFull);
    }
}

// ---------------------------------------------------------------------------
// FUSED: a = h + segment_sum(bf16(h)[src] * w) ; hnext = relu(a @ W + b).
// Phase 1 (latency-bound gather): the wave-wide coalesced pair prefetch for
// node t+1 is issued BEFORE node t's gather loop, so its latency hides under
// the gathers. Accumulation order is identical to the unpipelined version.
// ---------------------------------------------------------------------------
__global__ __launch_bounds__(256) void agg_gemm_kernel(
        const float* __restrict__ h,               // layer-l activations (f32)
        const __hip_bfloat16* __restrict__ hbf_in, // layer-l activations (bf16)
        const int* __restrict__ offs,
        const int* __restrict__ counts,
        const int2* __restrict__ pairs,
        const unsigned short* __restrict__ wf,     // fragment-order W (bf16 bits)
        const float* __restrict__ b,
        float* __restrict__ hnext,
        __hip_bfloat16* __restrict__ hbf_out,
        const int store_bf) {
    __shared__ unsigned short sX[64 * PITCH_HID];  // 11264 B
    const int tid  = threadIdx.x;
    const int row0 = blockIdx.x * 64;
    const int lane = tid & 63;
    const int wid  = tid >> 6;
    const int grp  = lane >> 4;
    const int sub  = lane & 15;

    const int node0 = row0 + wid * 16;
    int beg_n = 0, cnt_n = 0;
    if (node0 < N_NODES) { beg_n = offs[node0]; cnt_n = counts[node0]; }
    int2 pl = pairs[min(beg_n + lane, PAIRS_LIM)];

    // ---- Phase 1: aggregate 16 nodes per wave into LDS (bf16) ----
    for (int t = 0; t < 16; ++t) {
        const int node = node0 + t;                // wave-uniform
        const int beg  = beg_n;
        const int cnt  = cnt_n;
        const int2 pl_cur = pl;
        if (t < 15) {                              // prefetch next node's pairs
            int nn = node + 1;
            if (nn < N_NODES) { beg_n = offs[nn]; cnt_n = counts[nn]; }
            else              { beg_n = 0;        cnt_n = 0; }
            pl = pairs[min(beg_n + lane, PAIRS_LIM)];
        }
        if (node < N_NODES) {
            float ax = 0.f, ay = 0.f, az = 0.f, aw = 0.f;
            {   // chunk 0: pairs already resident in pl_cur
                const int nb   = min(64, cnt);
                const int last = nb - 1;
                for (int i = 0; i < nb; i += 8) {
                    int e0 = i + grp;
                    int e1 = i + 4 + grp;
                    bool l0 = (e0 <= last);
                    bool l1 = (e1 <= last);
                    int s0  = __shfl(pl_cur.x, l0 ? e0 : last);
                    int w0i = __shfl(pl_cur.y, l0 ? e0 : last);
                    int s1  = __shfl(pl_cur.x, l1 ? e1 : last);
                    int w1i = __shfl(pl_cur.y, l1 ? e1 : last);
                    uint2 g0 = *(const uint2*)(hbf_in + (size_t)s0 * HID + sub * 4);
                    uint2 g1 = *(const uint2*)(hbf_in + (size_t)s1 * HID + sub * 4);
                    float w0 = l0 ? __int_as_float(w0i) : 0.0f;
                    float w1 = l1 ? __int_as_float(w1i) : 0.0f;
                    ax += w0 * __uint_as_float(g0.x << 16);
                    ay += w0 * __uint_as_float(g0.x & 0xFFFF0000u);
                    az += w0 * __uint_as_float(g0.y << 16);
                    aw += w0 * __uint_as_float(g0.y & 0xFFFF0000u);
                    ax += w1 * __uint_as_float(g1.x << 16);
                    ay += w1 * __uint_as_float(g1.x & 0xFFFF0000u);
                    az += w1 * __uint_as_float(g1.y << 16);
                    aw += w1 * __uint_as_float(g1.y & 0xFFFF0000u);
                }
            }
            for (int j0 = 64; j0 < cnt; j0 += 64) {   // rare: degree > 64
                int2 pl2 = pairs[min(beg + j0 + lane, PAIRS_LIM)];
                const int nb   = min(64, cnt - j0);
                const int last = nb - 1;
                for (int i = 0; i < nb; i += 8) {
                    int e0 = i + grp;
                    int e1 = i + 4 + grp;
                    bool l0 = (e0 <= last);
                    bool l1 = (e1 <= last);
                    int s0  = __shfl(pl2.x, l0 ? e0 : last);
                    int w0i = __shfl(pl2.y, l0 ? e0 : last);
                    int s1  = __shfl(pl2.x, l1 ? e1 : last);
                    int w1i = __shfl(pl2.y, l1 ? e1 : last);
                    uint2 g0 = *(const uint2*)(hbf_in + (size_t)s0 * HID + sub * 4);
                    uint2 g1 = *(const uint2*)(hbf_in + (size_t)s1 * HID + sub * 4);
                    float w0 = l0 ? __int_as_float(w0i) : 0.0f;
                    float w1 = l1 ? __int_as_float(w1i) : 0.0f;
                    ax += w0 * __uint_as_float(g0.x << 16);
                    ay += w0 * __uint_as_float(g0.x & 0xFFFF0000u);
                    az += w0 * __uint_as_float(g0.y << 16);
                    aw += w0 * __uint_as_float(g0.y & 0xFFFF0000u);
                    ax += w1 * __uint_as_float(g1.x << 16);
                    ay += w1 * __uint_as_float(g1.x & 0xFFFF0000u);
                    az += w1 * __uint_as_float(g1.y << 16);
                    aw += w1 * __uint_as_float(g1.y & 0xFFFF0000u);
                }
            }
            ax += __shfl_xor(ax, 16); ay += __shfl_xor(ay, 16);
            az += __shfl_xor(az, 16); aw += __shfl_xor(aw, 16);
            ax += __shfl_xor(ax, 32); ay += __shfl_xor(ay, 32);
            az += __shfl_xor(az, 32); aw += __shfl_xor(aw, 32);
            if (grp == 0) {
                const float4 hv = *(const float4*)(h + (size_t)node * HID + sub * 4);
                ushort4 pk;
                pk.x = f2bf(hv.x + ax); pk.y = f2bf(hv.y + ay);
                pk.z = f2bf(hv.z + az); pk.w = f2bf(hv.w + aw);
                *(ushort4*)(sX + (wid * 16 + t) * PITCH_HID + sub * 4) = pk;
            }
        } else if (grp == 0) {
            ushort4 z; z.x = 0; z.y = 0; z.z = 0; z.w = 0;
            *(ushort4*)(sX + (wid * 16 + t) * PITCH_HID + sub * 4) = z;
        }
    }
    __syncthreads();

    // ---- Phase 2: 16x16x32 bf16 MFMA (K=64) + relu epilogue ----
    const int l16 = lane & 15;
    const int q   = lane >> 4;

    f32x4 acc[4] = {{0,0,0,0},{0,0,0,0},{0,0,0,0},{0,0,0,0}};
    const bf16x8* wf8 = (const bf16x8*)wf;

    #pragma unroll
    for (int kc = 0; kc < 2; ++kc) {
        bf16x8 af = *(const bf16x8*)(sX + (wid * 16 + l16) * PITCH_HID + kc * 32 + q * 8);
        #pragma unroll
        for (int nt = 0; nt < 4; ++nt) {
            bf16x8 bfr = wf8[((kc * 4 + nt) * 4 + q) * 16 + l16];
            acc[nt] = __builtin_amdgcn_mfma_f32_16x16x32_bf16(af, bfr, acc[nt], 0, 0, 0);
        }
    }

    #pragma unroll
    for (int nt = 0; nt < 4; ++nt) {
        float bb = b[nt * 16 + l16];
        #pragma unroll
        for (int reg = 0; reg < 4; ++reg) {
            int rg = row0 + wid * 16 + q * 4 + reg;
            if (rg < N_NODES) {
                float v = fmaxf(acc[nt][reg] + bb, 0.0f);
                hnext[(size_t)rg * HID + nt * 16 + l16] = v;
                if (store_bf)
                    hbf_out[(size_t)rg * HID + nt * 16 + l16] = __float2bfloat16(v);
            }
        }
    }
}

extern "C" void kernel_launch(void* const* d_in, const int* in_sizes, int n_in,
                              void* d_out, int out_size, void* d_ws, size_t ws_size,
                              hipStream_t stream) {
    const float* x   = (const float*)d_in[0];
    const int*   ei  = (const int*)  d_in[1];   // (2, E): [src | tgt]
    const float* ea  = (const float*)d_in[2];
    const float* Wi  = (const float*)d_in[3];
    const float* bi  = (const float*)d_in[4];
    const float* W1  = (const float*)d_in[5];
    const float* b1  = (const float*)d_in[6];
    const float* W2  = (const float*)d_in[7];
    const float* b2  = (const float*)d_in[8];
    const float* W3  = (const float*)d_in[9];
    const float* b3  = (const float*)d_in[10];
    const float* bl[3] = { b1, b2, b3 };
    float* out = (float*)d_out;  // (4, N, HID)

    const int* src = ei;
    const int* tgt = ei + N_EDGES;

    // Workspace layout (padded bins; hbf double-buffered).
    unsigned long long* binned = (unsigned long long*)d_ws;          // NBINS*CAP * 8B (25.6 MB)
    int* offs         = (int*)(binned + (size_t)NBINS * CAP);
    int* counts       = offs + N_NODES;
    int* g_bin_cursor = counts + N_NODES;
    int* pad          = g_bin_cursor + NBINS;                        // keep 8B align
    unsigned long long* pairs = (unsigned long long*)(pad + 1);      // NBINS*CAP * 8B
    __hip_bfloat16* hbf0 = (__hip_bfloat16*)(pairs + (size_t)NBINS * CAP);
    __hip_bfloat16* hbf1 = hbf0 + (size_t)N_NODES * HID;             // N*HID bf16
    unsigned short* wf_in  = (unsigned short*)(hbf1 + (size_t)N_NODES * HID);
    unsigned short* wf_hid = wf_in + 8192;                           // 3 x 4096

    wf_prep_kernel<<<32, 256, 0, stream>>>(Wi, W1, W2, W3, wf_in, wf_hid,
                                           g_bin_cursor);

    const int eb_blocks = (N_EDGES + EB - 1) / EB;  // 782
    scatter_sort_kernel<<<eb_blocks, 256, 0, stream>>>(src, tgt, ea,
                                                       g_bin_cursor, binned);
    fine_fill_kernel   <<<NBINS, 1024, 0, stream>>>(binned, g_bin_cursor,
                                                    offs, counts, pairs);

    const int gemm_blocks = (N_NODES + 63) / 64;  // 1563
    gemm_in_kernel<<<gemm_blocks, 256, 0, stream>>>(x, wf_in, bi, out, hbf0);

    __hip_bfloat16* hin  = hbf0;
    __hip_bfloat16* hout = hbf1;
    for (int l = 0; l < 3; ++l) {
        const float* hl = out + (size_t)l * N_NODES * HID;
        float* hn       = out + (size_t)(l + 1) * N_NODES * HID;
        agg_gemm_kernel<<<gemm_blocks, 256, 0, stream>>>(
            hl, hin, offs, counts, (const int2*)pairs,
            wf_hid + (size_t)l * 4096, bl[l], hn, hout, (l < 2) ? 1 : 0);
        __hip_bfloat16* t = hin; hin = hout; hout = t;
    }
}